// Round 12
// baseline (117.235 us; speedup 1.0000x reference)
//
#include <hip/hip_runtime.h>
#include <math.h>

constexpr int Bn = 256;
constexpr int Tn = 4096;
constexpr int Sn = 32;
constexpr int NE = 8;             // eighths per row (K1 granularity)
constexpr int EL = Tn / NE;       // 512
constexpr int WPE = 8;            // 64-step windows per eighth
constexpr int NT2 = 256;          // K2 threads: 8 tc-groups x 32 states (4 waves)
constexpr int TCN = NT2 / Sn;     // 8
constexpr int TL = EL / TCN;      // 64 contiguous t per thread
constexpr int CL = 16;            // chunk length
constexpr int CPT = TL / CL;      // 4 chunks per thread
constexpr float HALF_LN2PI = 0.918938533204672742f;
constexpr float SAT = -3.0e38f;   // final clamp (ref hits -inf; only NaN fails)
constexpr float PCLAMP = 1.0e38f; // keep power multipliers finite (never 0*inf)

// ws float offsets (~4.5 MB used)
constexpr size_t OFF_LF = 0;                                 // [Bn][NE][Sn] fwd eighth aggregates
constexpr size_t OFF_LB = (size_t)Bn * NE * Sn;              // [Bn][NE][Sn] bwd eighth aggregates
constexpr size_t OFF_PF = OFF_LB + (size_t)Bn * NE * Sn;     // [Bn][NE][7][Sn] fwd prefixes at t=64k+63
constexpr size_t OFF_SB = OFF_PF + (size_t)Bn * NE * 7 * Sn; // [Bn][NE][7][Sn] bwd suffixes m_{64k-1}

// NaN-safety invariant (per lane s): all per-step g-terms < 0 => f/b <= 0; +inf
// unreachable. w>1 lanes may reach -inf (their multipliers >=1, clamped <=1e38:
// never 0*inf). w<1 lanes stay finite when multipliers underflow to 0.
// exp(v<=0) <= 1. Clamp once at the store => output finite, never NaN.

#define DPP_ROR_ADD(x, ctrl) \
    ((x) + __int_as_float(__builtin_amdgcn_update_dpp(0, __float_as_int(x), (ctrl), 0xF, 0xF, false)))

// K1: per (b,e,s) thread: interleaved fwd/bwd zero-carry scans of its eighth;
// records 64-step boundary values + eighth aggregates. (round-9 proven; unroll 1/2
// to avoid the round-8 VGPR=256 spill)
__global__ __launch_bounds__(256) void hmm_agg_kernel(
    const float* __restrict__ obvs, const float* __restrict__ ln_pi,
    const float* __restrict__ trans_w, const float* __restrict__ trans_b,
    const float* __restrict__ mu, const float* __restrict__ log_sigma,
    float* __restrict__ ws)
{
    const int gid = blockIdx.x * 256 + threadIdx.x;   // 65536
    const int s = gid & 31;
    const int e = (gid >> 5) & (NE - 1);
    const int b = gid >> 8;
    const float w  = trans_w[s];
    const float tb = trans_b[s];
    const float pi = ln_pi[s];
    const float m  = mu[s];
    const float ls = log_sigma[s];
    const float inv = __expf(-ls);
    const float cqa  = -0.5f * inv * inv;
    const float cqb  = m * inv * inv;
    const float cqcb = -ls - HALF_LN2PI - 0.5f * m * m * inv * inv + tb; // emit + tb folded
    const float tbb  = tb - w * tb;

    const float4* base = (const float4*)(obvs + (size_t)b * Tn + (size_t)e * EL);
    float a = 0.f, lb = 0.f;
#pragma unroll 1
    for (int k = 0; k < WPE; ++k) {
        const int kk = WPE - 1 - k;        // bwd consumes blocks top-down
#pragma unroll 2
        for (int j4 = 0; j4 < 16; ++j4) {
            float4 x = base[k * 16 + j4];
            float4 y = base[kk * 16 + (15 - j4)];
            float g0 = fmaf(fmaf(cqa, x.x, cqb), x.x, cqcb);
            float g1 = fmaf(fmaf(cqa, x.y, cqb), x.y, cqcb);
            float g2 = fmaf(fmaf(cqa, x.z, cqb), x.z, cqcb);
            float g3 = fmaf(fmaf(cqa, x.w, cqb), x.w, cqcb);
            if (e == 0 && k == 0 && j4 == 0) g0 += pi - tb;
            a = fmaf(w, a, g0);
            a = fmaf(w, a, g1);
            a = fmaf(w, a, g2);
            a = fmaf(w, a, g3);
            float d3 = fmaf(fmaf(cqa, y.w, cqb), y.w, cqcb);
            float d2 = fmaf(fmaf(cqa, y.z, cqb), y.z, cqcb);
            float d1 = fmaf(fmaf(cqa, y.y, cqb), y.y, cqcb);
            float d0 = fmaf(fmaf(cqa, y.x, cqb), y.x, cqcb);
            lb = fmaf(w, lb + d3, tbb);
            lb = fmaf(w, lb + d2, tbb);
            lb = fmaf(w, lb + d1, tbb);
            lb = fmaf(w, lb + d0, tbb);
        }
        if (k < WPE - 1) {
            ws[OFF_PF + ((size_t)(b * NE + e) * 7 + k) * Sn + s] = a;          // after fwd block k
            ws[OFF_SB + ((size_t)(b * NE + e) * 7 + (kk - 1)) * Sn + s] = lb;  // m_{64*kk - 1}
        }
    }
    ws[OFF_LF + (size_t)(b * NE + e) * Sn + s] = a;
    ws[OFF_LB + (size_t)(b * NE + e) * Sn + s] = lb;
}

// K2: block (b, eighth); carries read from ws (no Phase A/B, one barrier);
// LDS obvs; wave-local transpose tile -> dwordx4 stores.
__global__ __launch_bounds__(NT2, 8) void hmm_main_kernel(
    const float* __restrict__ obvs, const float* __restrict__ ln_pi,
    const float* __restrict__ trans_w, const float* __restrict__ trans_b,
    const float* __restrict__ mu, const float* __restrict__ log_sigma,
    float* __restrict__ out, const float* __restrict__ ws)
{
    __shared__ __align__(16) float s_obvs[EL];          // 2 KB
    __shared__ __align__(16) float s_tile[4][2][8][Sn]; // 8 KB: per-wave transpose tiles

    const int be  = blockIdx.x;
    const int b   = be >> 3;
    const int e   = be & (NE - 1);
    const int tid = threadIdx.x;
    const int s   = tid & 31;
    const int tc  = tid >> 5;        // 0..7
    const int wv  = tid >> 6;        // wave 0..3
    const int tcl = (tid >> 5) & 1;  // tc within wave
    const int lane = tid & 63;
    const int t0  = tc * TL;

    if (tid < EL / 4)
        ((float4*)s_obvs)[tid] = ((const float4*)(obvs + (size_t)b * Tn + (size_t)e * EL))[tid];

    const float w  = trans_w[s];
    const float tb = trans_b[s];
    const float pi = ln_pi[s];
    const float m  = mu[s];
    const float ls = log_sigma[s];
    const float inv = __expf(-ls);
    const float cqa  = -0.5f * inv * inv;
    const float cqb  = m * inv * inv;
    const float cqcb = -ls - HALF_LN2PI - 0.5f * m * m * inv * inv + tb;
    const float tbb  = tb - w * tb;
    float w16; { float w2 = w * w, w4 = w2 * w2; float w8 = w4 * w4; w16 = w8 * w8; }
    const float w32 = fminf(w16 * w16, PCLAMP);
    const float w48 = fminf(w32 * w16, PCLAMP);
    const float l2w = log2f(w);
    const float WEL = fminf(exp2f(l2w * 512.0f), PCLAMP);                 // w^512
    const float pY  = fminf(exp2f(l2w * (float)(TL * tc)), PCLAMP);       // w^(64*tc)
    const float pX  = fminf(exp2f(l2w * (float)(TL * (7 - tc))), PCLAMP); // w^(64*(7-tc))
    const bool th0  = (e == 0) && (tc == 0);

    __syncthreads();

#define EMIT(xv) fmaf(fmaf(cqa, (xv), cqb), (xv), cqcb)

    // ---- cross-eighth carries from ws (L2-coalesced per half-wave) ----
    float Y = 0.f;                               // true f entering eighth e
#pragma unroll
    for (int qq = 0; qq < NE - 1; ++qq)
        if (qq < e) Y = fmaf(WEL, Y, ws[OFF_LF + (size_t)(b * NE + qq) * Sn + s]);
    float xT = obvs[(size_t)b * Tn + Tn - 1];
    float X = EMIT(xT) + (pi - tb);              // b_{T-1}
#pragma unroll
    for (int qq = NE - 1; qq > 0; --qq)
        if (qq > e) X = fmaf(WEL, X, ws[OFF_LB + (size_t)(b * NE + qq) * Sn + s]);
    // X = true b at last t of eighth e

    // ---- window carries from K1 boundary values ----
    const float fprev = tc ? ws[OFF_PF + ((size_t)(b * NE + e) * 7 + (tc - 1)) * Sn + s] : 0.f;
    float f = fmaf(pY, Y, fprev);                // true f at window start - 1
    const float msuf = (tc < 7) ? ws[OFF_SB + ((size_t)(b * NE + e) * 7 + tc) * Sn + s] : 0.f;
    const float Xth = fmaf(pX, X, msuf);         // true b at window's last t

    // ---- sweep1: chunk-local bwd partials (emit in place) ----
    float lbs[CPT];
#pragma unroll
    for (int i = 0; i < CPT; ++i) {
        const float4* q4 = (const float4*)(s_obvs + t0 + i * CL);
        float4 v0 = q4[0], v1 = q4[1], v2 = q4[2], v3 = q4[3];
        float x[CL] = {v0.x, v0.y, v0.z, v0.w, v1.x, v1.y, v1.z, v1.w,
                       v2.x, v2.y, v2.z, v2.w, v3.x, v3.y, v3.z, v3.w};
#pragma unroll
        for (int j = 0; j < CL; ++j) x[j] = EMIT(x[j]);
        float l = 0.f;
#pragma unroll
        for (int j = CL - 2; j >= -1; --j)
            l = fmaf(w, l + x[j + 1], tbb);
        lbs[i] = l;
    }
    const float Z3 = lbs[3];
    const float Z2 = fmaf(w16, Z3, lbs[2]);
    const float Z1 = fmaf(w16, Z2, lbs[1]);
    float Rarr[CPT];
    Rarr[3] = Xth;
    Rarr[2] = fmaf(w16, Xth, Z3);
    Rarr[1] = fmaf(w32, Xth, Z2);
    Rarr[0] = fmaf(w48, Xth, Z1);

    const size_t rowbase = (size_t)b * Tn + (size_t)e * EL;   // in t-rows
    const int qr  = lane & 7;
    const int t8r = (lane >> 3) & 7;

    // ---- sweep2: fwd chain + chunk bwd fill + LSE; transpose tile + x4 stores ----
#pragma unroll
    for (int i = 0; i < CPT; ++i) {
        const float4* q4 = (const float4*)(s_obvs + t0 + i * CL);
        float4 v0 = q4[0], v1 = q4[1], v2 = q4[2], v3 = q4[3];
        float x[CL] = {v0.x, v0.y, v0.z, v0.w, v1.x, v1.y, v1.z, v1.w,
                       v2.x, v2.y, v2.z, v2.w, v3.x, v3.y, v3.z, v3.w};
#pragma unroll
        for (int j = 0; j < CL; ++j) x[j] = EMIT(x[j]);     // ev in place
        if (th0 && i == 0) x[0] += pi - tb;                 // t==0 uses pi

        float barr[CL];
        barr[CL - 1] = Rarr[i];
#pragma unroll
        for (int j = CL - 2; j >= 0; --j)
            barr[j] = fmaf(w, barr[j + 1] + x[j + 1], tbb);

#pragma unroll
        for (int h = 0; h < 2; ++h) {
#pragma unroll
            for (int j8 = 0; j8 < 8; ++j8) {
                const int j = h * 8 + j8;
                f = fmaf(w, f, x[j]);
                float v = f + barr[j];
                float sum = __expf(v);                 // v <= 0
                sum = DPP_ROR_ADD(sum, 0x121);         // row_ror:1
                sum = DPP_ROR_ADD(sum, 0x122);         // row_ror:2
                sum = DPP_ROR_ADD(sum, 0x124);         // row_ror:4
                sum = DPP_ROR_ADD(sum, 0x128);         // row_ror:8 -> row sums
                {   // cross-row (xor-16) on the VALU pipe: permlane16_swap(x,x)
                    // result is a 2-elem vector: [0]=even-row sums, [1]=odd-row sums,
                    // both replicated to all rows; their sum = 32-lane total.
                    auto r = __builtin_amdgcn_permlane16_swap(
                        __float_as_uint(sum), __float_as_uint(sum), false, false);
                    sum = __uint_as_float(r[0]) + __uint_as_float(r[1]);
                }
                sum = fmaxf(sum, 1.0e-35f);
                s_tile[wv][tcl][j8][s] = fmaxf(v - __logf(sum), SAT);
            }
            // wave-local flush: 2 x (ds_read_b128 + 1KB-contiguous dwordx4 store)
#pragma unroll
            for (int r2 = 0; r2 < 2; ++r2) {
                float4 val = *(const float4*)&s_tile[wv][r2][t8r][qr * 4];
                const int trow = (wv * 2 + r2) * TL + i * CL + h * 8 + t8r;
                *(float4*)(out + ((rowbase + trow) << 5) + qr * 4) = val;
            }
        }
    }
#undef EMIT
}

extern "C" void kernel_launch(void* const* d_in, const int* in_sizes, int n_in,
                              void* d_out, int out_size, void* d_ws, size_t ws_size,
                              hipStream_t stream)
{
    const float* obvs      = (const float*)d_in[0];
    const float* ln_pi     = (const float*)d_in[1];
    const float* trans_w   = (const float*)d_in[2];
    const float* trans_b   = (const float*)d_in[3];
    const float* mu        = (const float*)d_in[4];
    const float* log_sigma = (const float*)d_in[5];
    float* out = (float*)d_out;
    float* wsf = (float*)d_ws;    // ~4.5 MB used

    hipLaunchKernelGGL(hmm_agg_kernel, dim3(Bn * NE * Sn / 256), dim3(256), 0, stream,
                       obvs, ln_pi, trans_w, trans_b, mu, log_sigma, wsf);
    hipLaunchKernelGGL(hmm_main_kernel, dim3(Bn * NE), dim3(NT2), 0, stream,
                       obvs, ln_pi, trans_w, trans_b, mu, log_sigma, out, wsf);
}

// Round 13
// 55.825 us; speedup vs baseline: 2.1001x; 2.1001x over previous
//
#include <hip/hip_runtime.h>
#include <math.h>

constexpr int Bn = 256;
constexpr int Tn = 4096;
constexpr int Sn = 32;
constexpr int NE = 8;             // eighths per row
constexpr int EL = Tn / NE;       // 512
constexpr int NT2 = 256;          // K2 threads: 8 tc-groups x 32 states (4 waves)
constexpr int TCN = NT2 / Sn;     // 8
constexpr int TL = EL / TCN;      // 64 contiguous t per thread
constexpr int CL = 16;            // chunk length
constexpr int CPT = TL / CL;      // 4 chunks per thread
constexpr float HALF_LN2PI = 0.918938533204672742f;
constexpr float SAT = -3.0e38f;   // final clamp (ref hits -inf; only NaN fails)
constexpr float PCLAMP = 1.0e38f; // keep power multipliers finite (never 0*inf)

constexpr size_t OFF_LF = 0;                      // ws: [Bn][NE][Sn] fwd eighth aggregates
constexpr size_t OFF_LB = (size_t)Bn * NE * Sn;   // ws: [Bn][NE][Sn] bwd eighth aggregates

// NaN-safety invariant (per lane s): all per-step g-terms < 0 => f/b <= 0; +inf
// unreachable. w>1 lanes may reach -inf (their multipliers >=1, clamped <=1e38:
// never 0*inf). w<1 lanes stay finite when multipliers underflow to 0.
// exp(v<=0) <= 1. Clamp once at the store => output finite, never NaN.

#define DPP_ROR_ADD(x, ctrl) \
    ((x) + __int_as_float(__builtin_amdgcn_update_dpp(0, __float_as_int(x), (ctrl), 0xF, 0xF, false)))

// K1: per (b,e,s) thread: interleaved fwd/bwd zero-carry scans of its eighth;
// stores only the two aggregates. (round-7/10 proven; do NOT split the chains —
// round-8's split version spilled at VGPR=256)
__global__ __launch_bounds__(256) void hmm_agg_kernel(
    const float* __restrict__ obvs, const float* __restrict__ ln_pi,
    const float* __restrict__ trans_w, const float* __restrict__ trans_b,
    const float* __restrict__ mu, const float* __restrict__ log_sigma,
    float* __restrict__ ws)
{
    const int gid = blockIdx.x * 256 + threadIdx.x;   // 65536
    const int s = gid & 31;
    const int e = (gid >> 5) & (NE - 1);
    const int b = gid >> 8;
    const float w  = trans_w[s];
    const float tb = trans_b[s];
    const float pi = ln_pi[s];
    const float m  = mu[s];
    const float ls = log_sigma[s];
    const float inv = __expf(-ls);
    const float cqa  = -0.5f * inv * inv;
    const float cqb  = m * inv * inv;
    const float cqcb = -ls - HALF_LN2PI - 0.5f * m * m * inv * inv + tb; // emit + tb
    const float tbb  = tb - w * tb;

    const float4* base = (const float4*)(obvs + (size_t)b * Tn + (size_t)e * EL);
    float a = 0.f, lb = 0.f;
#pragma unroll 4
    for (int j4 = 0; j4 < EL / 4; ++j4) {
        float4 x = base[j4];
        float4 y = base[EL / 4 - 1 - j4];
        float g0 = fmaf(fmaf(cqa, x.x, cqb), x.x, cqcb);
        float g1 = fmaf(fmaf(cqa, x.y, cqb), x.y, cqcb);
        float g2 = fmaf(fmaf(cqa, x.z, cqb), x.z, cqcb);
        float g3 = fmaf(fmaf(cqa, x.w, cqb), x.w, cqcb);
        if (e == 0 && j4 == 0) g0 += pi - tb;
        a = fmaf(w, a, g0);
        a = fmaf(w, a, g1);
        a = fmaf(w, a, g2);
        a = fmaf(w, a, g3);
        float d3 = fmaf(fmaf(cqa, y.w, cqb), y.w, cqcb);
        float d2 = fmaf(fmaf(cqa, y.z, cqb), y.z, cqcb);
        float d1 = fmaf(fmaf(cqa, y.y, cqb), y.y, cqcb);
        float d0 = fmaf(fmaf(cqa, y.x, cqb), y.x, cqcb);
        lb = fmaf(w, lb + d3, tbb);
        lb = fmaf(w, lb + d2, tbb);
        lb = fmaf(w, lb + d1, tbb);
        lb = fmaf(w, lb + d0, tbb);
    }
    ws[OFF_LF + (size_t)(b * NE + e) * Sn + s] = a;
    ws[OFF_LB + (size_t)(b * NE + e) * Sn + s] = lb;
}

// K2: block (b, eighth). LDS obvs; in-block Phase A (proven clean: no spill);
// Phase B = 1 barrier + per-thread predicated combine; LSE fully on VALU;
// wave-local transpose tile -> 1KB-contiguous dwordx4 stores.
__global__ __launch_bounds__(NT2, 8) void hmm_main_kernel(
    const float* __restrict__ obvs, const float* __restrict__ ln_pi,
    const float* __restrict__ trans_w, const float* __restrict__ trans_b,
    const float* __restrict__ mu, const float* __restrict__ log_sigma,
    float* __restrict__ out, const float* __restrict__ ws)
{
    __shared__ __align__(16) float s_obvs[EL];          // 2 KB
    __shared__ float s_PF[TCN][Sn];                     // 1 KB: raw thread fwd aggregates
    __shared__ float s_ZB[TCN][Sn];                     // 1 KB: raw thread bwd aggregates
    __shared__ __align__(16) float s_tile[4][2][8][Sn]; // 8 KB: per-wave transpose tiles

    const int be  = blockIdx.x;
    const int b   = be >> 3;
    const int e   = be & (NE - 1);
    const int tid = threadIdx.x;
    const int s   = tid & 31;
    const int tc  = tid >> 5;        // 0..7
    const int wv  = tid >> 6;        // wave 0..3
    const int tcl = (tid >> 5) & 1;  // tc within wave
    const int lane = tid & 63;
    const int t0  = tc * TL;

    if (tid < EL / 4)
        ((float4*)s_obvs)[tid] = ((const float4*)(obvs + (size_t)b * Tn + (size_t)e * EL))[tid];

    const float w  = trans_w[s];
    const float tb = trans_b[s];
    const float pi = ln_pi[s];
    const float m  = mu[s];
    const float ls = log_sigma[s];
    const float inv = __expf(-ls);
    const float cqa  = -0.5f * inv * inv;
    const float cqb  = m * inv * inv;
    const float cqcb = -ls - HALF_LN2PI - 0.5f * m * m * inv * inv + tb;
    const float tbb  = tb - w * tb;
    float w16; { float w2 = w * w, w4 = w2 * w2; float w8 = w4 * w4; w16 = w8 * w8; }
    const float w32 = fminf(w16 * w16, PCLAMP);
    const float w48 = fminf(w32 * w16, PCLAMP);
    const float W64 = fminf(w32 * w32, PCLAMP);
    const float l2w = log2f(w);
    const float WEL = fminf(exp2f(l2w * 512.0f), PCLAMP);                 // w^512
    const float pY  = fminf(exp2f(l2w * (float)(TL * tc)), PCLAMP);       // w^(64*tc)
    const float pX  = fminf(exp2f(l2w * (float)(TL * (7 - tc))), PCLAMP); // w^(64*(7-tc))
    const bool th0  = (e == 0) && (tc == 0);

    __syncthreads();

#define EMIT(xv) fmaf(fmaf(cqa, (xv), cqb), (xv), cqcb)

    // ---- Phase A: thread-local zero-carry scans (EMIT once, in place) ----
    float lbs[CPT];
    float AF = 0.f;
#pragma unroll
    for (int i = 0; i < CPT; ++i) {
        const float4* q4 = (const float4*)(s_obvs + t0 + i * CL);
        float4 v0 = q4[0], v1 = q4[1], v2 = q4[2], v3 = q4[3];
        float x[CL] = {v0.x, v0.y, v0.z, v0.w, v1.x, v1.y, v1.z, v1.w,
                       v2.x, v2.y, v2.z, v2.w, v3.x, v3.y, v3.z, v3.w};
#pragma unroll
        for (int j = 0; j < CL; ++j) x[j] = EMIT(x[j]);
#pragma unroll
        for (int j = 0; j < CL; ++j) {
            float g = x[j];
            if (th0 && i == 0 && j == 0) g += pi - tb;
            AF = fmaf(w, AF, g);
        }
        float l = 0.f;
#pragma unroll
        for (int j = CL - 2; j >= -1; --j)
            l = fmaf(w, l + x[j + 1], tbb);
        lbs[i] = l;
    }
    const float Z3 = lbs[3];
    const float Z2 = fmaf(w16, Z3, lbs[2]);
    const float Z1 = fmaf(w16, Z2, lbs[1]);
    const float ZT = fmaf(w16, Z1, lbs[0]);

    s_PF[tc][s] = AF;
    s_ZB[tc][s] = ZT;
    __syncthreads();

    // ---- Phase B: per-thread predicated combine of the 8 raw aggregates ----
    float P = 0.f, Zs = 0.f;
#pragma unroll
    for (int k = 0; k < TCN - 1; ++k) {          // k = 0..6 ; k2 = 7..1
        const int k2 = TCN - 1 - k;
        float vF = s_PF[k][s];
        float vB = s_ZB[k2][s];
        if (k < tc)  P  = fmaf(W64, P,  vF);     // inclusive prefix ending at tc-1
        if (k2 > tc) Zs = fmaf(W64, Zs, vB);     // inclusive suffix starting at tc+1
    }

    // ---- cross-eighth carries from ws ----
    float Y = 0.f;
#pragma unroll
    for (int qq = 0; qq < NE - 1; ++qq)
        if (qq < e) Y = fmaf(WEL, Y, ws[OFF_LF + (size_t)(b * NE + qq) * Sn + s]);
    float xT = obvs[(size_t)b * Tn + Tn - 1];
    float X = EMIT(xT) + (pi - tb);              // b_{T-1}
#pragma unroll
    for (int qq = NE - 1; qq > 0; --qq)
        if (qq > e) X = fmaf(WEL, X, ws[OFF_LB + (size_t)(b * NE + qq) * Sn + s]);

    // ---- thread-level carries ----
    float f         = fmaf(pY, Y, P);            // true f at t0 - 1
    const float Xth = fmaf(pX, X, Zs);           // true b at thread's last t
    float Rarr[CPT];
    Rarr[3] = Xth;
    Rarr[2] = fmaf(w16, Xth, Z3);
    Rarr[1] = fmaf(w32, Xth, Z2);
    Rarr[0] = fmaf(w48, Xth, Z1);

    const size_t rowbase = (size_t)b * Tn + (size_t)e * EL;   // in t-rows
    const int qr  = lane & 7;
    const int t8r = (lane >> 3) & 7;

    // ---- Phase C: fwd chain + chunk bwd fill + LSE; transpose tile + x4 stores ----
#pragma unroll
    for (int i = 0; i < CPT; ++i) {
        const float4* q4 = (const float4*)(s_obvs + t0 + i * CL);
        float4 v0 = q4[0], v1 = q4[1], v2 = q4[2], v3 = q4[3];
        float x[CL] = {v0.x, v0.y, v0.z, v0.w, v1.x, v1.y, v1.z, v1.w,
                       v2.x, v2.y, v2.z, v2.w, v3.x, v3.y, v3.z, v3.w};
#pragma unroll
        for (int j = 0; j < CL; ++j) x[j] = EMIT(x[j]);     // ev in place
        if (th0 && i == 0) x[0] += pi - tb;                 // t==0 uses pi

        float barr[CL];
        barr[CL - 1] = Rarr[i];
#pragma unroll
        for (int j = CL - 2; j >= 0; --j)
            barr[j] = fmaf(w, barr[j + 1] + x[j + 1], tbb);

#pragma unroll
        for (int h = 0; h < 2; ++h) {
#pragma unroll
            for (int j8 = 0; j8 < 8; ++j8) {
                const int j = h * 8 + j8;
                f = fmaf(w, f, x[j]);
                float v = f + barr[j];
                float sum = __expf(v);                 // v <= 0
                sum = DPP_ROR_ADD(sum, 0x121);         // row_ror:1
                sum = DPP_ROR_ADD(sum, 0x122);         // row_ror:2
                sum = DPP_ROR_ADD(sum, 0x124);         // row_ror:4
                sum = DPP_ROR_ADD(sum, 0x128);         // row_ror:8 -> per-row sums
                {   // cross-row (xor-16) on VALU: permlane16_swap (verified R12)
                    auto r = __builtin_amdgcn_permlane16_swap(
                        __float_as_uint(sum), __float_as_uint(sum), false, false);
                    sum = __uint_as_float(r[0]) + __uint_as_float(r[1]);
                }
                sum = fmaxf(sum, 1.0e-35f);
                s_tile[wv][tcl][j8][s] = fmaxf(v - __logf(sum), SAT);
            }
            // wave-local flush: 2 x (ds_read_b128 + 1KB-contiguous dwordx4 store)
#pragma unroll
            for (int r2 = 0; r2 < 2; ++r2) {
                float4 val = *(const float4*)&s_tile[wv][r2][t8r][qr * 4];
                const int trow = (wv * 2 + r2) * TL + i * CL + h * 8 + t8r;
                *(float4*)(out + ((rowbase + trow) << 5) + qr * 4) = val;
            }
        }
    }
#undef EMIT
}

extern "C" void kernel_launch(void* const* d_in, const int* in_sizes, int n_in,
                              void* d_out, int out_size, void* d_ws, size_t ws_size,
                              hipStream_t stream)
{
    const float* obvs      = (const float*)d_in[0];
    const float* ln_pi     = (const float*)d_in[1];
    const float* trans_w   = (const float*)d_in[2];
    const float* trans_b   = (const float*)d_in[3];
    const float* mu        = (const float*)d_in[4];
    const float* log_sigma = (const float*)d_in[5];
    float* out = (float*)d_out;
    float* wsf = (float*)d_ws;    // 256 KB used

    hipLaunchKernelGGL(hmm_agg_kernel, dim3(Bn * NE * Sn / 256), dim3(256), 0, stream,
                       obvs, ln_pi, trans_w, trans_b, mu, log_sigma, wsf);
    hipLaunchKernelGGL(hmm_main_kernel, dim3(Bn * NE), dim3(NT2), 0, stream,
                       obvs, ln_pi, trans_w, trans_b, mu, log_sigma, out, wsf);
}

// Round 14
// 47.750 us; speedup vs baseline: 2.4552x; 1.1691x over previous
//
#include <hip/hip_runtime.h>
#include <math.h>

constexpr int Bn = 256;
constexpr int Tn = 4096;
constexpr int Sn = 32;
constexpr int NE = 8;             // eighths per row
constexpr int EL = Tn / NE;       // 512
constexpr int NT2 = 256;          // threads: 8 tc-groups x 32 states (4 waves)
constexpr int TCN = NT2 / Sn;     // 8
constexpr int TL = EL / TCN;      // 64 contiguous t per thread
constexpr int CL = 16;            // chunk length
constexpr int CPT = TL / CL;      // 4 chunks per thread
constexpr float HALF_LN2PI = 0.918938533204672742f;
constexpr float SAT = -3.0e38f;   // final clamp (ref hits -inf; only NaN fails)
constexpr float PCLAMP = 1.0e38f; // keep power multipliers finite (never 0*inf)

constexpr size_t OFF_LF = 0;                      // ws: [Bn][NE][Sn] fwd eighth aggregates
constexpr size_t OFF_LB = (size_t)Bn * NE * Sn;   // ws: [Bn][NE][Sn] bwd eighth aggregates

// NaN-safety invariant (per lane s): all per-step g-terms < 0 => f/b <= 0; +inf
// unreachable. w>1 lanes may reach -inf (their multipliers >=1, clamped <=1e38:
// never 0*inf). w<1 lanes stay finite when multipliers underflow to 0.
// exp(v<=0) <= 1. Clamp once at the store => output finite, never NaN.

#define DPP_ROR_ADD(x, ctrl) \
    ((x) + __int_as_float(__builtin_amdgcn_update_dpp(0, __float_as_int(x), (ctrl), 0xF, 0xF, false)))

// K1: block (b, eighth) — same skeleton as K2's Phase A+B (proven clean codegen).
// Per-thread 64-step window scans -> 3-round KS -> write the two eighth aggregates.
__global__ __launch_bounds__(NT2, 8) void hmm_agg_kernel(
    const float* __restrict__ obvs, const float* __restrict__ ln_pi,
    const float* __restrict__ trans_w, const float* __restrict__ trans_b,
    const float* __restrict__ mu, const float* __restrict__ log_sigma,
    float* __restrict__ ws)
{
    __shared__ __align__(16) float s_obvs[EL];   // 2 KB
    __shared__ float s_PF[TCN][Sn];              // 1 KB
    __shared__ float s_ZB[TCN][Sn];              // 1 KB

    const int be  = blockIdx.x;
    const int b   = be >> 3;
    const int e   = be & (NE - 1);
    const int tid = threadIdx.x;
    const int s   = tid & 31;
    const int tc  = tid >> 5;        // 0..7
    const int t0  = tc * TL;

    if (tid < EL / 4)
        ((float4*)s_obvs)[tid] = ((const float4*)(obvs + (size_t)b * Tn + (size_t)e * EL))[tid];

    const float w  = trans_w[s];
    const float tb = trans_b[s];
    const float pi = ln_pi[s];
    const float m  = mu[s];
    const float ls = log_sigma[s];
    const float inv = __expf(-ls);
    const float cqa  = -0.5f * inv * inv;
    const float cqb  = m * inv * inv;
    const float cqcb = -ls - HALF_LN2PI - 0.5f * m * m * inv * inv + tb;
    const float tbb  = tb - w * tb;
    float w16; { float w2 = w * w, w4 = w2 * w2; float w8 = w4 * w4; w16 = w8 * w8; }
    const float w32 = fminf(w16 * w16, PCLAMP);
    const float W64 = fminf(w32 * w32, PCLAMP);
    const bool th0  = (e == 0) && (tc == 0);

    __syncthreads();

#define EMIT(xv) fmaf(fmaf(cqa, (xv), cqb), (xv), cqcb)

    // ---- window scans (identical to K2 Phase A) ----
    float lbs[CPT];
    float AF = 0.f;
#pragma unroll
    for (int i = 0; i < CPT; ++i) {
        const float4* q4 = (const float4*)(s_obvs + t0 + i * CL);
        float4 v0 = q4[0], v1 = q4[1], v2 = q4[2], v3 = q4[3];
        float x[CL] = {v0.x, v0.y, v0.z, v0.w, v1.x, v1.y, v1.z, v1.w,
                       v2.x, v2.y, v2.z, v2.w, v3.x, v3.y, v3.z, v3.w};
#pragma unroll
        for (int j = 0; j < CL; ++j) {
            float g = EMIT(x[j]);
            if (th0 && i == 0 && j == 0) g += pi - tb;
            AF = fmaf(w, AF, g);
        }
        float l = 0.f;
#pragma unroll
        for (int j = CL - 2; j >= -1; --j)
            l = fmaf(w, l + EMIT(x[j + 1]), tbb);
        lbs[i] = l;
    }
    const float Z3 = lbs[3];
    const float Z2 = fmaf(w16, Z3, lbs[2]);
    const float Z1 = fmaf(w16, Z2, lbs[1]);
    const float ZT = fmaf(w16, Z1, lbs[0]);

    s_PF[tc][s] = AF;
    s_ZB[tc][s] = ZT;
    __syncthreads();

    // ---- 3-round Kogge-Stone (identical to K2 Phase B) ----
    {
        float Wd = W64;
#pragma unroll
        for (int r = 0; r < 3; ++r) {
            const int d = 1 << r;
            float tF = (tc >= d)      ? s_PF[tc - d][s] : 0.f;
            float tB = (tc + d < TCN) ? s_ZB[tc + d][s] : 0.f;
            __syncthreads();
            if (tc >= d)      s_PF[tc][s] = fmaf(Wd, tF, s_PF[tc][s]);
            if (tc + d < TCN) s_ZB[tc][s] = fmaf(Wd, tB, s_ZB[tc][s]);
            Wd = fminf(Wd * Wd, PCLAMP);
            __syncthreads();
        }
    }

    if (tc == 7) ws[OFF_LF + (size_t)be * Sn + s] = s_PF[TCN - 1][s];  // full fwd aggregate
    if (tc == 0) ws[OFF_LB + (size_t)be * Sn + s] = s_ZB[0][s];        // full bwd aggregate
#undef EMIT
}

// K2: block (b, eighth). R10-verbatim (best measured): LDS obvs; in-block Phase A;
// 3-round KS Phase B; DPP+shfl LSE; wave-local transpose tile -> dwordx4 stores.
__global__ __launch_bounds__(NT2, 8) void hmm_main_kernel(
    const float* __restrict__ obvs, const float* __restrict__ ln_pi,
    const float* __restrict__ trans_w, const float* __restrict__ trans_b,
    const float* __restrict__ mu, const float* __restrict__ log_sigma,
    float* __restrict__ out, const float* __restrict__ ws)
{
    __shared__ __align__(16) float s_obvs[EL];          // 2 KB
    __shared__ float s_PF[TCN][Sn];                     // 1 KB
    __shared__ float s_ZB[TCN][Sn];                     // 1 KB
    __shared__ __align__(16) float s_tile[4][2][8][Sn]; // 8 KB: per-wave transpose tiles

    const int be  = blockIdx.x;
    const int b   = be >> 3;
    const int e   = be & (NE - 1);
    const int tid = threadIdx.x;
    const int s   = tid & 31;
    const int tc  = tid >> 5;        // 0..7
    const int wv  = tid >> 6;        // wave 0..3
    const int tcl = (tid >> 5) & 1;  // tc within wave
    const int lane = tid & 63;
    const int t0  = tc * TL;

    if (tid < EL / 4)
        ((float4*)s_obvs)[tid] = ((const float4*)(obvs + (size_t)b * Tn + (size_t)e * EL))[tid];

    const float w  = trans_w[s];
    const float tb = trans_b[s];
    const float pi = ln_pi[s];
    const float m  = mu[s];
    const float ls = log_sigma[s];
    const float inv = __expf(-ls);
    const float cqa  = -0.5f * inv * inv;
    const float cqb  = m * inv * inv;
    const float cqcb = -ls - HALF_LN2PI - 0.5f * m * m * inv * inv + tb;
    const float tbb  = tb - w * tb;
    float w16; { float w2 = w * w, w4 = w2 * w2; float w8 = w4 * w4; w16 = w8 * w8; }
    const float w32 = fminf(w16 * w16, PCLAMP);
    const float w48 = fminf(w32 * w16, PCLAMP);
    const float W64 = fminf(w32 * w32, PCLAMP);
    const float l2w = log2f(w);
    const float WEL = fminf(exp2f(l2w * 512.0f), PCLAMP);                 // w^512
    const float pY  = fminf(exp2f(l2w * (float)(TL * tc)), PCLAMP);       // w^(64*tc)
    const float pX  = fminf(exp2f(l2w * (float)(TL * (7 - tc))), PCLAMP); // w^(64*(7-tc))
    const bool th0  = (e == 0) && (tc == 0);

    __syncthreads();

#define EMIT(xv) fmaf(fmaf(cqa, (xv), cqb), (xv), cqcb)

    // ---- Phase A: thread-local zero-carry scans ----
    float lbs[CPT];
    float AF = 0.f;
#pragma unroll
    for (int i = 0; i < CPT; ++i) {
        const float4* q4 = (const float4*)(s_obvs + t0 + i * CL);
        float4 v0 = q4[0], v1 = q4[1], v2 = q4[2], v3 = q4[3];
        float x[CL] = {v0.x, v0.y, v0.z, v0.w, v1.x, v1.y, v1.z, v1.w,
                       v2.x, v2.y, v2.z, v2.w, v3.x, v3.y, v3.z, v3.w};
#pragma unroll
        for (int j = 0; j < CL; ++j) {
            float g = EMIT(x[j]);
            if (th0 && i == 0 && j == 0) g += pi - tb;
            AF = fmaf(w, AF, g);
        }
        float l = 0.f;
#pragma unroll
        for (int j = CL - 2; j >= -1; --j)
            l = fmaf(w, l + EMIT(x[j + 1]), tbb);
        lbs[i] = l;
    }
    const float Z3 = lbs[3];
    const float Z2 = fmaf(w16, Z3, lbs[2]);
    const float Z1 = fmaf(w16, Z2, lbs[1]);
    const float ZT = fmaf(w16, Z1, lbs[0]);

    s_PF[tc][s] = AF;
    s_ZB[tc][s] = ZT;
    __syncthreads();

    // ---- Phase B: 3-round Kogge-Stone over the 8 thread aggregates ----
    {
        float Wd = W64;
#pragma unroll
        for (int r = 0; r < 3; ++r) {
            const int d = 1 << r;
            float tF = (tc >= d)      ? s_PF[tc - d][s] : 0.f;
            float tB = (tc + d < TCN) ? s_ZB[tc + d][s] : 0.f;
            __syncthreads();
            if (tc >= d)      s_PF[tc][s] = fmaf(Wd, tF, s_PF[tc][s]);
            if (tc + d < TCN) s_ZB[tc][s] = fmaf(Wd, tB, s_ZB[tc][s]);
            Wd = fminf(Wd * Wd, PCLAMP);
            __syncthreads();
        }
    }

    // ---- cross-eighth carries from ws ----
    float Y = 0.f;
#pragma unroll
    for (int qq = 0; qq < NE - 1; ++qq)
        if (qq < e) Y = fmaf(WEL, Y, ws[OFF_LF + (size_t)(b * NE + qq) * Sn + s]);
    float xT = obvs[(size_t)b * Tn + Tn - 1];
    float X = EMIT(xT) + (pi - tb);              // b_{T-1}
#pragma unroll
    for (int qq = NE - 1; qq > 0; --qq)
        if (qq > e) X = fmaf(WEL, X, ws[OFF_LB + (size_t)(b * NE + qq) * Sn + s]);

    // ---- thread-level carries ----
    const float Pprev  = (tc > 0)       ? s_PF[tc - 1][s] : 0.f;
    const float ZSnext = (tc < TCN - 1) ? s_ZB[tc + 1][s] : 0.f;
    float f         = fmaf(pY, Y, Pprev);        // true f at t0 - 1
    const float Xth = fmaf(pX, X, ZSnext);       // true b at thread's last t
    float Rarr[CPT];
    Rarr[3] = Xth;
    Rarr[2] = fmaf(w16, Xth, Z3);
    Rarr[1] = fmaf(w32, Xth, Z2);
    Rarr[0] = fmaf(w48, Xth, Z1);

    const size_t rowbase = (size_t)b * Tn + (size_t)e * EL;   // in t-rows
    const int qr  = lane & 7;
    const int t8r = (lane >> 3) & 7;

    // ---- Phase C: fwd chain + chunk bwd fill + LSE; transpose tile + x4 stores ----
#pragma unroll
    for (int i = 0; i < CPT; ++i) {
        const float4* q4 = (const float4*)(s_obvs + t0 + i * CL);
        float4 v0 = q4[0], v1 = q4[1], v2 = q4[2], v3 = q4[3];
        float x[CL] = {v0.x, v0.y, v0.z, v0.w, v1.x, v1.y, v1.z, v1.w,
                       v2.x, v2.y, v2.z, v2.w, v3.x, v3.y, v3.z, v3.w};
        float barr[CL];
        barr[CL - 1] = Rarr[i];
#pragma unroll
        for (int j = CL - 2; j >= 0; --j)
            barr[j] = fmaf(w, barr[j + 1] + EMIT(x[j + 1]), tbb);

#pragma unroll
        for (int h = 0; h < 2; ++h) {
#pragma unroll
            for (int j8 = 0; j8 < 8; ++j8) {
                const int j = h * 8 + j8;
                float g = EMIT(x[j]);
                if (th0 && i == 0 && j == 0) g += pi - tb;
                f = fmaf(w, f, g);
                float v = f + barr[j];
                float sum = __expf(v);                 // v <= 0
                sum = DPP_ROR_ADD(sum, 0x121);         // row_ror:1
                sum = DPP_ROR_ADD(sum, 0x122);         // row_ror:2
                sum = DPP_ROR_ADD(sum, 0x124);         // row_ror:4
                sum = DPP_ROR_ADD(sum, 0x128);         // row_ror:8
                sum += __shfl_xor(sum, 16, 32);
                sum = fmaxf(sum, 1.0e-35f);
                s_tile[wv][tcl][j8][s] = fmaxf(v - __logf(sum), SAT);
            }
            // wave-local flush: 2 x (ds_read_b128 + 1KB-contiguous dwordx4 store)
#pragma unroll
            for (int r2 = 0; r2 < 2; ++r2) {
                float4 val = *(const float4*)&s_tile[wv][r2][t8r][qr * 4];
                const int trow = (wv * 2 + r2) * TL + i * CL + h * 8 + t8r;
                *(float4*)(out + ((rowbase + trow) << 5) + qr * 4) = val;
            }
        }
    }
#undef EMIT
}

extern "C" void kernel_launch(void* const* d_in, const int* in_sizes, int n_in,
                              void* d_out, int out_size, void* d_ws, size_t ws_size,
                              hipStream_t stream)
{
    const float* obvs      = (const float*)d_in[0];
    const float* ln_pi     = (const float*)d_in[1];
    const float* trans_w   = (const float*)d_in[2];
    const float* trans_b   = (const float*)d_in[3];
    const float* mu        = (const float*)d_in[4];
    const float* log_sigma = (const float*)d_in[5];
    float* out = (float*)d_out;
    float* wsf = (float*)d_ws;    // 256 KB used

    hipLaunchKernelGGL(hmm_agg_kernel, dim3(Bn * NE), dim3(NT2), 0, stream,
                       obvs, ln_pi, trans_w, trans_b, mu, log_sigma, wsf);
    hipLaunchKernelGGL(hmm_main_kernel, dim3(Bn * NE), dim3(NT2), 0, stream,
                       obvs, ln_pi, trans_w, trans_b, mu, log_sigma, out, wsf);
}